// Round 1
// baseline (183.406 us; speedup 1.0000x reference)
//
#include <hip/hip_runtime.h>

// Gaussian covariance-from-scaling+quaternion:
//   s = exp(scaling_raw); R = quat_to_rot(normalize(rotation));
//   L = R * diag(s); cov = L L^T; out = upper-triangular 6 elems.
// Memory-bound: 28 B in + 24 B out per gaussian. One gaussian per thread,
// grid-stride, vectorized loads/stores where alignment permits.

__global__ __launch_bounds__(256) void gauss_cov_kernel(
    const float* __restrict__ sr,      // (N,3) f32
    const float4* __restrict__ rot,    // (N,4) f32
    float* __restrict__ out,           // (N,6) f32
    int n)
{
    int stride = gridDim.x * blockDim.x;
    for (int i = blockIdx.x * blockDim.x + threadIdx.x; i < n; i += stride) {
        // rotation: aligned float4 load (16 B/lane, coalesced)
        float4 q = rot[i];
        float inv = rsqrtf(q.x * q.x + q.y * q.y + q.z * q.z + q.w * q.w);
        float w = q.x * inv, x = q.y * inv, y = q.z * inv, z = q.w * inv;

        // scaling: 3 contiguous f32 (compiler merges; L1 absorbs 12 B stride)
        size_t si = (size_t)i * 3;
        float s0 = expf(sr[si + 0]);
        float s1 = expf(sr[si + 1]);
        float s2 = expf(sr[si + 2]);

        float xx = x * x, yy = y * y, zz = z * z;
        float xy = x * y, xz = x * z, yz = y * z;
        float wx = w * x, wy = w * y, wz = w * z;

        float R00 = 1.f - 2.f * (yy + zz), R01 = 2.f * (xy - wz), R02 = 2.f * (xz + wy);
        float R10 = 2.f * (xy + wz), R11 = 1.f - 2.f * (xx + zz), R12 = 2.f * (yz - wx);
        float R20 = 2.f * (xz - wy), R21 = 2.f * (yz + wx), R22 = 1.f - 2.f * (xx + yy);

        float L00 = R00 * s0, L01 = R01 * s1, L02 = R02 * s2;
        float L10 = R10 * s0, L11 = R11 * s1, L12 = R12 * s2;
        float L20 = R20 * s0, L21 = R21 * s1, L22 = R22 * s2;

        float c00 = L00 * L00 + L01 * L01 + L02 * L02;
        float c01 = L00 * L10 + L01 * L11 + L02 * L12;
        float c02 = L00 * L20 + L01 * L21 + L02 * L22;
        float c11 = L10 * L10 + L11 * L11 + L12 * L12;
        float c12 = L10 * L20 + L11 * L21 + L12 * L22;
        float c22 = L20 * L20 + L21 * L21 + L22 * L22;

        // 6 f32 out, row starts at 24 B offset -> 8 B aligned: three float2 stores
        float2* o = (float2*)(out + (size_t)i * 6);
        o[0] = make_float2(c00, c01);
        o[1] = make_float2(c02, c11);
        o[2] = make_float2(c12, c22);
    }
}

extern "C" void kernel_launch(void* const* d_in, const int* in_sizes, int n_in,
                              void* d_out, int out_size, void* d_ws, size_t ws_size,
                              hipStream_t stream) {
    const float*  sr  = (const float*)d_in[0];   // (N,3)
    const float4* rot = (const float4*)d_in[1];  // (N,4)
    float* out = (float*)d_out;                  // (N,6)
    int n = in_sizes[0] / 3;

    const int block = 256;
    int grid = (n + block - 1) / block;
    if (grid > 2048) grid = 2048;
    gauss_cov_kernel<<<grid, block, 0, stream>>>(sr, rot, out, n);
}